// Round 3
// baseline (404.022 us; speedup 1.0000x reference)
//
#include <hip/hip_runtime.h>

// SpatialCorrelationSampler: out[b,(dy+4)*9+(dx+4),y,x] =
//   sum_c f0[b,c,y,x]*f1[b,c,y+dy,x+dx], dy,dx in [-4,4], OOB=0.
// B=4 C=256 H=96 W=160 -> out (4,81,96,160) fp32.
//
// R7: R4-R6 post-mortem: SQ_LDS_BANK_CONFLICT bit-identical (7741440)
// across 3 layouts/read-mixes -> reads contribute ZERO conflicts; it's
// 18 staging writes x 56cyc, layout-invariant (not fixable). R6's f0-LDS
// regressed (+768cyc/stage reads). Real gap: ~2800cyc/stage convoy stall
// at 1 block/CU (grid 240!), 2.25 waves/SIMD: all 9 waves burst LDS, FMA,
// then converge on one barrier + vmcnt(0) drain of sunk prefetch (VGPR 68
// = acc36+p0 exactly -> pipeline regs never held). Per-CU LDS pipe floor
// ~50us; overlap is the missing piece -> need 2 blocks/CU. Grid pinned at
// 240 tiles and RX=4 sliding window is the optimal read shape, so the only
// duplication-free split is CHANNELS: 480 blocks = 240 tiles x 2 C-halves
// (pair on same XCD), 16 stages, 2 blocks/CU (96KB LDS, 18 waves=4.5/SIMD)
// -> blocks de-phase, compute covers the other's barrier/drain.
// Combine: last-block ticket in ws (partial store + fence + atomic ticket;
// loser sums both halves -> out). Fallback: memset(out)+atomicAdd.
// Wave w owns dy = w-4; 16x16 tile, RX=4, acc[9][4]=36 regs.

#define Bn 4
#define Cn 256
#define CHALF 128
#define Hn 96
#define Wn 160
#define HWn (Hn * Wn)
#define NP 81
#define TY 16
#define TX 16
#define CCH 8                   // channels per stage
#define NSTAGE (CHALF / CCH)    // 16
#define WROWS (TY + 8)          // 24
#define SEGS 6                  // float4 segments per 24-float data row
#define LROW 32                 // padded+swizzled LDS row stride (floats)
#define F1C (WROWS * LROW)      // 768 floats per staged channel
#define BUF (CCH * F1C)         // 6144 floats per LDS buffer
#define NT 576                  // 9 waves
#define F1STG (CCH * HWn / 4)   // float4 stride between stages in f1
#define NPART (Bn * NP * Hn * Wn)             // 4976640 floats per partial
#define WS_NEED ((size_t)NPART * 8 + 4096)    // 2 partials + tickets

__global__ __launch_bounds__(NT, 2) void corr_kernel(const float* __restrict__ f0,
                                                     const float* __restrict__ f1,
                                                     float* __restrict__ out,
                                                     float* __restrict__ pbuf,
                                                     int* __restrict__ tickets,
                                                     int use_ws) {
    __shared__ __align__(16) float lds[2 * BUF];  // 49152 B double buffer
    __shared__ int who;

    const int tid  = threadIdx.x;
    const int wave = tid >> 6;      // 0..8 (dy = wave-4)
    const int lane = tid & 63;
    const int r    = lane >> 2;     // 0..15 tile row
    const int g    = lane & 3;      // 0..3  col group of 4 px

    // 480 blocks = 8 XCDs x {30 tiles x 2 halves}. Same-tile pair shares XCD.
    const int blk  = blockIdx.x;
    const int xcd  = blk & 7;
    const int it2  = blk >> 3;          // 0..59
    const int half = it2 / 30;          // 0..1 channel half
    const int it   = it2 % 30;          // 0..29 tile within XCD
    const int b    = xcd >> 1;
    const int ty   = (xcd & 1) * 3 + it / 10;
    const int tx   = it % 10;
    const int y0   = ty * TY;
    const int x0   = tx * TX;
    const int ch0  = half * CHALF;
    const int tile_id = xcd * 30 + it;  // 0..239 unique per spatial tile

    // ---- f1 staging map: 2 float4/thread/stage; copy 2 = same spot, ch +4
    const int scc  = tid / (WROWS * SEGS);        // 0..3
    const int srm  = tid - scc * (WROWS * SEGS);
    const int srr  = srm / SEGS;                  // 0..23 window row
    const int sseg = srm - srr * SEGS;            // 0..5
    const int sgy  = y0 - 4 + srr;
    const int sgx  = x0 - 4 + sseg * 4;           // mult of 4 -> all-in/out of [0,W)
    const bool sval = (sgy >= 0) && (sgy < Hn) && (sgx >= 0) && (sgx < Wn);
    const int swz   = (sseg * 4) ^ ((srr & 1) << 4);
    const int slidx = (scc * F1C + srr * LROW + swz) >> 2;        // float4 idx
    const int sgidx = sval ? ((((b * Cn + ch0 + scc) * Hn + sgy) * Wn + sgx) >> 2) : 0;

    const float4* __restrict__ f1v = (const float4*)f1;
    float4* lv = (float4*)lds;

    // ---- read offsets (swizzle folded in, constant per lane)
    const int q  = r + wave;                      // 0..23 window row
    const int xr = (q & 1) << 4;
    const int o0 = q * LROW + ((g * 4) ^ xr);
    const int o1 = q * LROW + ((g * 4 + 4) ^ xr);
    const int o2 = q * LROW + ((g * 4 + 8) ^ xr);

    // ---- prologue: prefetch stage 0
    float4 p1a = make_float4(0.f, 0.f, 0.f, 0.f), p1b = p1a;
    if (sval) { p1a = f1v[sgidx]; p1b = f1v[sgidx + HWn]; }   // ch scc, scc+4

    const float* f0s = f0 + ((b * Cn + ch0) * Hn + y0 + r) * Wn + x0 + g * 4;
    float4 p0[CCH];
#pragma unroll
    for (int cc = 0; cc < CCH; ++cc) p0[cc] = *(const float4*)(f0s + cc * HWn);

    float acc[9][4];
#pragma unroll
    for (int i = 0; i < 9; ++i)
#pragma unroll
        for (int j = 0; j < 4; ++j) acc[i][j] = 0.f;

    for (int s = 0; s < NSTAGE; ++s) {
        float4* buf = lv + (s & 1) * (BUF / 4);
        buf[slidx]       = p1a;
        buf[slidx + F1C] = p1b;       // channel +4 -> +F1C float4
        __syncthreads();              // single barrier per stage

        // depth-1 prefetch for stage s+1
        const int ns = (s + 1 < NSTAGE) ? s + 1 : NSTAGE - 1;
        float4 n1a = make_float4(0.f, 0.f, 0.f, 0.f), n1b = n1a;
        if (sval) { n1a = f1v[sgidx + ns * F1STG]; n1b = f1v[sgidx + ns * F1STG + HWn]; }
        float4 n0[CCH];
#pragma unroll
        for (int cc = 0; cc < CCH; ++cc)
            n0[cc] = *(const float4*)(f0s + (ns * CCH + cc) * HWn);

        // compute stage s
        const float* base = &lds[(s & 1) * BUF];
#pragma unroll
        for (int cc = 0; cc < CCH; ++cc) {
            const float* wr = base + cc * F1C;
            float4 w0 = *(const float4*)(wr + o0);
            float4 w1 = *(const float4*)(wr + o1);
            float4 w2 = *(const float4*)(wr + o2);
            float av[4]  = {p0[cc].x, p0[cc].y, p0[cc].z, p0[cc].w};
            float wv[12] = {w0.x, w0.y, w0.z, w0.w, w1.x, w1.y, w1.z, w1.w,
                            w2.x, w2.y, w2.z, w2.w};
#pragma unroll
            for (int dx = 0; dx < 9; ++dx)
#pragma unroll
                for (int rx = 0; rx < 4; ++rx)
                    acc[dx][rx] = fmaf(av[rx], wv[rx + dx], acc[dx][rx]);
        }

        p1a = n1a; p1b = n1b;
#pragma unroll
        for (int cc = 0; cc < CCH; ++cc) p0[cc] = n0[cc];
    }

    // ---- epilogue: combine the two channel-halves
    const int orow = ((b * NP + wave * 9) * Hn + y0 + r) * Wn + x0 + g * 4;
    if (use_ws) {
        // store my partial, then last block of the pair sums both -> out
        float* pmine = pbuf + (size_t)half * NPART;
#pragma unroll
        for (int dx = 0; dx < 9; ++dx)
            *(float4*)(pmine + orow + dx * HWn) =
                make_float4(acc[dx][0], acc[dx][1], acc[dx][2], acc[dx][3]);
        __threadfence();
        __syncthreads();
        if (tid == 0) who = atomicAdd(&tickets[tile_id], 1);
        __syncthreads();
        if (who == 1) {
            __threadfence();
            const float* pother = pbuf + (size_t)(1 - half) * NPART;
#pragma unroll
            for (int dx = 0; dx < 9; ++dx) {
                float4 o = *(const float4*)(pother + orow + dx * HWn);
                *(float4*)(out + orow + dx * HWn) =
                    make_float4(acc[dx][0] + o.x, acc[dx][1] + o.y,
                                acc[dx][2] + o.z, acc[dx][3] + o.w);
            }
        }
    } else {
        // fallback: out pre-zeroed by host; accumulate atomically
#pragma unroll
        for (int dx = 0; dx < 9; ++dx)
#pragma unroll
            for (int rx = 0; rx < 4; ++rx)
                atomicAdd(out + orow + dx * HWn + rx, acc[dx][rx]);
    }
}

extern "C" void kernel_launch(void* const* d_in, const int* in_sizes, int n_in,
                              void* d_out, int out_size, void* d_ws, size_t ws_size,
                              hipStream_t stream) {
    const float* f0 = (const float*)d_in[0];
    const float* f1 = (const float*)d_in[1];
    float* out = (float*)d_out;
    int use_ws = (d_ws != nullptr && ws_size >= WS_NEED) ? 1 : 0;
    float* pbuf = (float*)d_ws;
    int* tickets = (int*)((char*)d_ws + (size_t)NPART * 8);
    if (use_ws) {
        hipMemsetAsync(tickets, 0, 240 * sizeof(int), stream);
    } else {
        hipMemsetAsync(d_out, 0, out_size, stream);
    }
    corr_kernel<<<dim3(480), NT, 0, stream>>>(f0, f1, out, pbuf, tickets, use_ws);
}

// Round 4
// 197.560 us; speedup vs baseline: 2.0451x; 2.0451x over previous
//
#include <hip/hip_runtime.h>

// SpatialCorrelationSampler: out[b,(dy+4)*9+(dx+4),y,x] =
//   sum_c f0[b,c,y,x]*f1[b,c,y+dy,x+dx], dy,dx in [-4,4], OOB=0.
// B=4 C=256 H=96 W=160 -> out (4,81,96,160) fp32.
//
// R8: revert R7 (ws too small -> atomic fallback, 310us). Base = R4/R5
// (86.8us). Remaining ~2800cyc/stage stall = __syncthreads' vmcnt(0)
// drain: every stage all 9 waves flush ALL in-flight global prefetch at
// the barrier (compiler also sank prefetch issues -- VGPR 68-84 = never
// held pipeline regs). The barrier only needs LDS ordering (dbuf parity
// proof: stage-s writes vs stage-(s-2) reads separated by barrier s-1;
// globals only touch regs). Fix:
//  (1) raw "s_waitcnt lgkmcnt(0); s_barrier" -- prefetch survives the
//      barrier (T4: never drain vmcnt in the main loop).
//  (2) sched_barrier(0) after prefetch issue -- stops the scheduler
//      sinking the loads back into the consuming stage.
// Wave w owns dy = w-4; 16x16 tile, RX=4, acc[9][4]=36 regs.

#define Bn 4
#define Cn 256
#define Hn 96
#define Wn 160
#define HWn (Hn * Wn)
#define NP 81
#define TY 16
#define TX 16
#define CCH 8                 // channels per stage
#define NSTAGE (Cn / CCH)     // 32
#define WROWS (TY + 8)        // 24
#define SEGS 6                // float4 segments per 24-float data row
#define LROW 32               // padded+swizzled LDS row stride (floats)
#define F1C (WROWS * LROW)    // 768 floats per staged channel
#define BUF (CCH * F1C)       // 6144 floats per LDS buffer
#define NT 576                // 9 waves
#define F1STG (CCH * HWn / 4) // float4 stride between stages in f1

// LDS-only barrier: order ds ops, do NOT drain vmcnt (global prefetch
// stays in flight across the barrier).
#define LDS_BAR() asm volatile("s_waitcnt lgkmcnt(0)\n\ts_barrier" ::: "memory")

__global__ __launch_bounds__(NT, 2) void corr_kernel(const float* __restrict__ f0,
                                                     const float* __restrict__ f1,
                                                     float* __restrict__ out) {
    __shared__ __align__(16) float lds[2 * BUF];  // 49152 B double buffer

    const int tid  = threadIdx.x;
    const int wave = tid >> 6;      // 0..8 (dy = wave-4)
    const int lane = tid & 63;
    const int r    = lane >> 2;     // 0..15 tile row
    const int g    = lane & 3;      // 0..3  col group of 4 px

    // XCD-spatial swizzle: 240 blocks = 8 XCDs x 30 tiles (half-batch each).
    const int blk = blockIdx.x;
    const int xcd = blk & 7;
    const int it  = blk >> 3;           // 0..29
    const int b   = xcd >> 1;
    const int ty  = (xcd & 1) * 3 + it / 10;
    const int tx  = it % 10;
    const int y0  = ty * TY;
    const int x0  = tx * TX;

    // ---- staging map: 2 float4/thread/stage; copy 2 = same spot, channel +4
    const int scc  = tid / (WROWS * SEGS);        // 0..3
    const int srm  = tid - scc * (WROWS * SEGS);
    const int srr  = srm / SEGS;                  // 0..23 window row
    const int sseg = srm - srr * SEGS;            // 0..5
    const int sgy  = y0 - 4 + srr;
    const int sgx  = x0 - 4 + sseg * 4;           // mult of 4 -> seg all-in/out of [0,W)
    const bool sval = (sgy >= 0) && (sgy < Hn) && (sgx >= 0) && (sgx < Wn);
    const int swz   = (sseg * 4) ^ ((srr & 1) << 4);              // XOR-16 row-parity swizzle
    const int slidx = (scc * F1C + srr * LROW + swz) >> 2;        // float4 idx
    const int sgidx = sval ? ((((b * Cn + scc) * Hn + sgy) * Wn + sgx) >> 2) : 0;

    const float4* __restrict__ f1v = (const float4*)f1;
    float4* lv = (float4*)lds;

    // ---- read offsets (swizzle folded in; reads proven conflict-free:
    // per 8-lane phase rows q/q+1 give disjoint quad sets for o0/o1/o2)
    const int q  = r + wave;                      // 0..23 window row
    const int xr = (q & 1) << 4;
    const int o0 = q * LROW + ((g * 4) ^ xr);
    const int o1 = q * LROW + ((g * 4 + 4) ^ xr);
    const int o2 = q * LROW + ((g * 4 + 8) ^ xr);

    // ---- prologue: prefetch stage 0
    float4 p1a = make_float4(0.f, 0.f, 0.f, 0.f), p1b = p1a;
    if (sval) { p1a = f1v[sgidx]; p1b = f1v[sgidx + HWn]; }   // ch scc, scc+4

    const float* f0s = f0 + ((b * Cn) * Hn + y0 + r) * Wn + x0 + g * 4;
    float4 p0[CCH];
#pragma unroll
    for (int cc = 0; cc < CCH; ++cc) p0[cc] = *(const float4*)(f0s + cc * HWn);

    float acc[9][4];
#pragma unroll
    for (int i = 0; i < 9; ++i)
#pragma unroll
        for (int j = 0; j < 4; ++j) acc[i][j] = 0.f;

    for (int s = 0; s < NSTAGE; ++s) {
        // publish stage s's f1 (auto vmcnt wait on p1 only -- issued a full
        // stage ago, long since landed). LDS_BAR makes writes visible
        // without draining the global prefetch queue.
        float4* buf = lv + (s & 1) * (BUF / 4);
        buf[slidx]       = p1a;
        buf[slidx + F1C] = p1b;       // channel +4 -> +F1C float4
        LDS_BAR();

        // issue stage s+1 prefetch NOW; sched_barrier pins it here so the
        // scheduler cannot sink the issues into the next stage.
        const int ns = (s + 1 < NSTAGE) ? s + 1 : NSTAGE - 1;
        float4 n1a = make_float4(0.f, 0.f, 0.f, 0.f), n1b = n1a;
        if (sval) { n1a = f1v[sgidx + ns * F1STG]; n1b = f1v[sgidx + ns * F1STG + HWn]; }
        float4 n0[CCH];
#pragma unroll
        for (int cc = 0; cc < CCH; ++cc)
            n0[cc] = *(const float4*)(f0s + (ns * CCH + cc) * HWn);
        __builtin_amdgcn_sched_barrier(0);

        // compute stage s (overlaps the in-flight prefetch)
        const float* base = &lds[(s & 1) * BUF];
#pragma unroll
        for (int cc = 0; cc < CCH; ++cc) {
            const float* wr = base + cc * F1C;
            float4 w0 = *(const float4*)(wr + o0);
            float4 w1 = *(const float4*)(wr + o1);
            float4 w2 = *(const float4*)(wr + o2);
            float av[4]  = {p0[cc].x, p0[cc].y, p0[cc].z, p0[cc].w};
            float wv[12] = {w0.x, w0.y, w0.z, w0.w, w1.x, w1.y, w1.z, w1.w,
                            w2.x, w2.y, w2.z, w2.w};
#pragma unroll
            for (int dx = 0; dx < 9; ++dx)
#pragma unroll
                for (int rx = 0; rx < 4; ++rx)
                    acc[dx][rx] = fmaf(av[rx], wv[rx + dx], acc[dx][rx]);
        }

        p1a = n1a; p1b = n1b;
#pragma unroll
        for (int cc = 0; cc < CCH; ++cc) p0[cc] = n0[cc];
    }

    // ---- epilogue: exclusive ownership -> plain coalesced float4 stores
    const int orow = ((b * NP + wave * 9) * Hn + y0 + r) * Wn + x0 + g * 4;
#pragma unroll
    for (int dx = 0; dx < 9; ++dx)
        *(float4*)(out + orow + dx * HWn) =
            make_float4(acc[dx][0], acc[dx][1], acc[dx][2], acc[dx][3]);
}

extern "C" void kernel_launch(void* const* d_in, const int* in_sizes, int n_in,
                              void* d_out, int out_size, void* d_ws, size_t ws_size,
                              hipStream_t stream) {
    const float* f0 = (const float*)d_in[0];
    const float* f1 = (const float*)d_in[1];
    float* out = (float*)d_out;
    corr_kernel<<<dim3(240), NT, 0, stream>>>(f0, f1, out);
}